// Round 1
// baseline (221.160 us; speedup 1.0000x reference)
//
#include <hip/hip_runtime.h>

// ScRRAMBLe capsule layer, two-kernel split, MLP-optimized.
//   A) xr[i,k,m] = sum_ij Ci[ij, i, k] * x[ij, m]    -> chunk partials in d_ws
//   B) y[i,j,l]  = sum_{k,m} Wi[i,j,k,l,m] * xr[i,k,m]
//
// R2 post-mortem: 4x occupancy gave ~0 speedup -> not wave-limited. VGPR=36
// shows the compiler kept only 4 Wi loads in flight per wave (vmcnt(0) per
// iter, full HBM latency each). R3: hoist all 16 loads (nontemporal) before
// any FMA; route reworked to i-quad blocks for full Ci cacheline use in L1.
// R4 (this round): infra failure on bench -> byte-identical resubmit to
// recover per-dispatch counters. Roofline arithmetic: Wi stream = 134 MB
// ~= 21 us; total floor ~25-30 us vs 223 us measured -> NOT at roofline,
// need the dispatch-level decomposition before restructuring.

typedef float f4 __attribute__((ext_vector_type(4)));

#define NCH 8   // ij chunks for routing kernel (xr partials: NCH*512*256 floats)

// ---------------- Kernel A: routing einsum ---------------------------------
// grid (128 i-quads, NCH); block 256.
// thread t: il = t>>6 (i within quad), g = (t>>4)&3 (ij subgroup), mq4 = t&15.
__global__ __launch_bounds__(256) void route_kernel(
    const float* __restrict__ x,
    const float* __restrict__ Ci,
    float* __restrict__ xr_part)
{
    const int iq  = blockIdx.x;
    const int c   = blockIdx.y;
    const int t   = threadIdx.x;
    const int il  = t >> 6;
    const int g   = (t >> 4) & 3;
    const int mq4 = t & 15;
    const int i   = (iq << 2) + il;

    const f4* __restrict__ Ci4 = (const f4*)Ci;
    const f4* __restrict__ x4  = (const f4*)x;

    __shared__ f4 part[1024];   // [g][il][r][mq4] = ((g*4+il)*4+r)*16+mq4

    f4 a0 = {0.f,0.f,0.f,0.f};
    f4 a1 = {0.f,0.f,0.f,0.f};
    f4 a2 = {0.f,0.f,0.f,0.f};
    f4 a3 = {0.f,0.f,0.f,0.f};

    const int ijpc = 2048 / NCH;      // 256
    const int sub  = ijpc >> 2;       // 64 per g-subgroup
    const int base = c * ijpc + g * sub;
    #pragma unroll 4
    for (int it = 0; it < sub; ++it) {
        const int ij = base + it;
        const f4 c4 = Ci4[ij * 512 + i];      // Ci[ij, i, 0:4] (16B of a 64B
                                              // line; other 3 i of the quad
                                              // consumed by sibling waves -> L1)
        const f4 xv = x4[(ij << 4) + mq4];    // x[ij, 4*mq4 .. +3]
        a0 += c4.x * xv;
        a1 += c4.y * xv;
        a2 += c4.z * xv;
        a3 += c4.w * xv;
    }

    const int pb = ((g << 2) + il) << 2;      // (g*4+il)*4
    part[(pb + 0) * 16 + mq4] = a0;
    part[(pb + 1) * 16 + mq4] = a1;
    part[(pb + 2) * 16 + mq4] = a2;
    part[(pb + 3) * 16 + mq4] = a3;
    __syncthreads();

    // reduce over g: thread t owns (il2 = t>>6, r = (t>>4)&3, mm = t&15)
    const int il2 = t >> 6;
    const int r   = (t >> 4) & 3;
    const int mm  = t & 15;
    f4 s = {0.f,0.f,0.f,0.f};
    #pragma unroll
    for (int gg = 0; gg < 4; ++gg)
        s += part[(((gg << 2) + il2) * 4 + r) * 16 + mm];

    f4* __restrict__ xp4 = (f4*)xr_part;
    xp4[(c * 512 + (iq << 2) + il2) * 64 + r * 16 + mm] = s;
}

// ---------------- Kernel B: per-capsule transform --------------------------
// grid 2048 = (i*4+j); block 256; wave w owns l in [w*16, w*16+16).
// All 16 Wi loads hoisted + nontemporal: 16 independent loads in flight/lane.
__global__ __launch_bounds__(256, 4) void transform_kernel(
    const float* __restrict__ Wi,
    const float* __restrict__ xr_part,
    float* __restrict__ y)
{
    const int b    = blockIdx.x;
    const int i    = b >> 2;
    const int t    = threadIdx.x;
    const int lane = t & 63;
    const int w    = t >> 6;
    const int lq   = lane >> 4;
    const int m16  = lane & 15;

    // Issue Wi loads FIRST (independent, nontemporal), then gather xr.
    const f4* __restrict__ W4 = (const f4*)Wi;
    const int wbase = b * 4096;
    const int lw    = w << 4;

    f4 wv[16];
    #pragma unroll
    for (int c2 = 0; c2 < 4; ++c2) {
        const int l = lw + (c2 << 2) + lq;
        #pragma unroll
        for (int k = 0; k < 4; ++k)
            wv[(c2 << 2) + k] =
                __builtin_nontemporal_load(&W4[wbase + (k << 10) + l * 16 + m16]);
    }

    // xr[i,k,m16*4..+3] summed over NCH chunk partials (L2/L3-resident).
    const f4* __restrict__ xp4 = (const f4*)xr_part;
    f4 xr0 = {0.f,0.f,0.f,0.f};
    f4 xr1 = {0.f,0.f,0.f,0.f};
    f4 xr2 = {0.f,0.f,0.f,0.f};
    f4 xr3 = {0.f,0.f,0.f,0.f};
    #pragma unroll
    for (int c = 0; c < NCH; ++c) {
        const int base = (c * 512 + i) * 64;
        xr0 += xp4[base + 0 * 16 + m16];
        xr1 += xp4[base + 1 * 16 + m16];
        xr2 += xp4[base + 2 * 16 + m16];
        xr3 += xp4[base + 3 * 16 + m16];
    }

    #pragma unroll
    for (int c2 = 0; c2 < 4; ++c2) {
        const int l = lw + (c2 << 2) + lq;
        f4 s = wv[(c2 << 2) + 0] * xr0
             + wv[(c2 << 2) + 1] * xr1
             + wv[(c2 << 2) + 2] * xr2
             + wv[(c2 << 2) + 3] * xr3;
        float p = s.x + s.y + s.z + s.w;
        p += __shfl_xor(p, 1);
        p += __shfl_xor(p, 2);
        p += __shfl_xor(p, 4);
        p += __shfl_xor(p, 8);
        if (m16 == 0) y[b * 64 + l] = p;
    }
}

extern "C" void kernel_launch(void* const* d_in, const int* in_sizes, int n_in,
                              void* d_out, int out_size, void* d_ws, size_t ws_size,
                              hipStream_t stream) {
    const float* x  = (const float*)d_in[0];   // 131072
    const float* Ci = (const float*)d_in[1];   // 512*4*512*4
    const float* Wi = (const float*)d_in[2];   // 512*4*4*64*64
    float* y  = (float*)d_out;                 // 512*4*64
    float* xr = (float*)d_ws;                  // NCH*512*256 floats = 4 MiB

    route_kernel<<<dim3(128, NCH), 256, 0, stream>>>(x, Ci, xr);
    transform_kernel<<<2048, 256, 0, stream>>>(Wi, xr, y);
}